// Round 15
// baseline (1687.948 us; speedup 1.0000x reference)
//
#include <hip/hip_runtime.h>
#include <hip/hip_bf16.h>
#include <stdint.h>

#define B_ 64
#define T_ 512
#define I_ 1024
#define H_ 1024
#define BH (B_*H_)

typedef __attribute__((ext_vector_type(8))) short short8;
typedef __attribute__((ext_vector_type(4))) float f32x4;
typedef __attribute__((ext_vector_type(4))) unsigned u32x4;
typedef __attribute__((ext_vector_type(2))) unsigned u32x2;

static __device__ __forceinline__ unsigned short f2bf(float f) {
  union { float f; unsigned u; } v; v.f = f;
  unsigned r = v.u + 0x7fffu + ((v.u >> 16) & 1u);
  return (unsigned short)(r >> 16);
}

static __device__ __forceinline__ void glds16(const void* g, void* l) {
  __builtin_amdgcn_global_load_lds(
      (const __attribute__((address_space(1))) unsigned int*)g,
      (__attribute__((address_space(3))) unsigned int*)l, 16, 0, 0);
}

// ---------------- weight conversion f32 -> bf16 ----------------
__global__ void convert_weights(const f32x4* __restrict__ wih, const f32x4* __restrict__ whh,
                                uint2* __restrict__ wih_b, uint2* __restrict__ whh_b)
{
  int idx = blockIdx.x * blockDim.x + threadIdx.x;
  f32x4 a = wih[idx];
  uint2 o;
  o.x = f2bf(a[0]) | ((unsigned)f2bf(a[1]) << 16);
  o.y = f2bf(a[2]) | ((unsigned)f2bf(a[3]) << 16);
  wih_b[idx] = o;
  f32x4 b = whh[idx];
  uint2 p;
  p.x = f2bf(b[0]) | ((unsigned)f2bf(b[1]) << 16);
  p.y = f2bf(b[2]) | ((unsigned)f2bf(b[3]) << 16);
  whh_b[idx] = p;
}

// ---------------- input conversion f32 -> bf16, A-row-major R=(t*64+b) ----------------
__global__ void convert_input(const float* __restrict__ in, unsigned short* __restrict__ inb)
{
  size_t idx = (size_t)blockIdx.x * 256 + threadIdx.x;
  size_t base = idx * 8;
  size_t R = base >> 10;
  int i = (int)(base & 1023);
  int b = (int)(R & 63), t = (int)(R >> 6);
  const float* src = in + ((size_t)b * T_ + (size_t)t) * I_ + i;
  f32x4 x0 = *(const f32x4*)src;
  f32x4 x1 = *(const f32x4*)(src + 4);
  uint4 o;
  o.x = f2bf(x0[0]) | ((unsigned)f2bf(x0[1]) << 16);
  o.y = f2bf(x0[2]) | ((unsigned)f2bf(x0[3]) << 16);
  o.z = f2bf(x1[0]) | ((unsigned)f2bf(x1[1]) << 16);
  o.w = f2bf(x1[2]) | ((unsigned)f2bf(x1[3]) << 16);
  *(uint4*)(inb + base) = o;
}

// ---------------- x_proj GEMM: both operands via global_load_lds ----------------
__launch_bounds__(256)
__global__ void gemm_xproj(const unsigned short* __restrict__ inb,
                           const unsigned short* __restrict__ wb,
                           const float* __restrict__ bih,
                           const float* __restrict__ bhh,
                           float* __restrict__ out)
{
  __shared__ __align__(16) unsigned char As[16384];
  __shared__ __align__(16) unsigned char Bs[16384];
  const int tid = threadIdx.x;
  const int lane = tid & 63;
  const int w = tid >> 6;
  const int wm = w >> 1, wn = w & 1;
  const int bn = blockIdx.x, bm = blockIdx.y;

  f32x4 acc[4][4];
  #pragma unroll
  for (int i = 0; i < 4; ++i)
    #pragma unroll
    for (int j = 0; j < 4; ++j)
      acc[i][j] = (f32x4){0.f,0.f,0.f,0.f};

  for (int kt = 0; kt < 16; ++kt) {
    __syncthreads();
    #pragma unroll
    for (int q = 0; q < 4; ++q) {
      int inst = w*4 + q;
      int rr = inst*8 + (lane >> 3);
      int soA = ((bm*128 + rr) * I_ + kt*64) * 2 + (((lane & 7) * 16) ^ ((rr & 7) << 4));
      int soB = ((bn*128 + rr) * I_ + kt*64) * 2 + (((lane & 7) * 16) ^ ((rr & 7) << 4));
      glds16((const unsigned char*)inb + soA, As + inst*1024);
      glds16((const unsigned char*)wb  + soB, Bs + inst*1024);
    }
    __syncthreads();
    #pragma unroll
    for (int kb = 0; kb < 2; ++kb) {
      const int kby = kb*64 + ((lane >> 4) << 4);
      short8 af[4], bfr[4];
      #pragma unroll
      for (int i = 0; i < 4; ++i) {
        int ra = wm*64 + i*16 + (lane & 15);
        af[i] = *(const short8*)(As + ra*128 + (kby ^ ((ra & 7) << 4)));
      }
      #pragma unroll
      for (int j = 0; j < 4; ++j) {
        int rb2 = wn*64 + j*16 + (lane & 15);
        bfr[j] = *(const short8*)(Bs + rb2*128 + (kby ^ ((rb2 & 7) << 4)));
      }
      #pragma unroll
      for (int i = 0; i < 4; ++i)
        #pragma unroll
        for (int j = 0; j < 4; ++j)
          acc[i][j] = __builtin_amdgcn_mfma_f32_16x16x32_bf16(af[i], bfr[j], acc[i][j], 0, 0, 0);
    }
  }
  #pragma unroll
  for (int j = 0; j < 4; ++j) {
    int col = bn*128 + wn*64 + j*16 + (lane & 15);
    float bias = bih[col] + bhh[col];
    #pragma unroll
    for (int i = 0; i < 4; ++i) {
      int Rb = bm*128 + wm*64 + i*16 + ((lane >> 4) << 2);
      #pragma unroll
      for (int q = 0; q < 4; ++q) {
        int R = Rb + q;
        out[(size_t)(R >> 6) * BH + (size_t)(R & 63) * H_ + col] = acc[i][j][q] + bias;
      }
    }
  }
}

// ---------------- recurrence: 32 WGs x 512 threads (4 gb x 8 gq, 128 cols/WG) ----------------
// Packet p = col4*16 + row (4096/gb): 16B = {4 bf16, tag=t+1, pad}, system-scope.
// Consumer thread: 8 packets p = j*512+tid (coalesced), partial miss-resweep.
// W_hh slice (128 cols x 1024 K) staged in 2 x 128KB rounds -> af[32] registers.
__launch_bounds__(512, 2)
__global__ void rnn_recur(const unsigned short* __restrict__ whh_b,
                          float* __restrict__ out,
                          unsigned char* __restrict__ hx)
{
  extern __shared__ __align__(16) unsigned char lds[];
  const int tid = threadIdx.x;
  const int lane = tid & 63;
  const int wv = tid >> 6;            // 0..7
  const int g = blockIdx.x;
  const int gb = g >> 3;              // 0..3: 16 batch rows
  const int gq = g & 7;               // 0..7: 128 H cols

  // ---- W_hh slice: 2 rounds of 128KB staging -> registers ----
  short8 af[32];
  const int wvr = wv & 3;
  const int arow_s = wvr*16 + (lane & 15);
  const unsigned char* wsrow = lds + (size_t)arow_s*2048;
  const int aswz = (arow_s & 7) << 4;
  const int klane = (lane >> 4) << 4;
  #pragma unroll
  for (int r = 0; r < 2; ++r) {
    #pragma unroll
    for (int q = 0; q < 16; ++q) {
      int inst = wv*16 + q;           // 0..127, 1KB each
      int nl = inst >> 1;             // staged local row 0..63
      int koff = (inst & 1)*1024 + lane*16;
      size_t srcoff = (size_t)(gq*128 + r*64 + nl)*2048 + (size_t)(koff ^ ((nl & 7) << 4));
      glds16((const unsigned char*)whh_b + srcoff, lds + inst*1024);
    }
    asm volatile("s_waitcnt vmcnt(0)" ::: "memory");
    __syncthreads();
    if ((wv >> 2) == r) {
      #pragma unroll
      for (int kb = 0; kb < 32; ++kb)
        af[kb] = *(const short8*)(wsrow + ((kb*64 + klane) ^ aswz));
    }
    __syncthreads();
  }

  const int bb = lane & 15;
  const int nq = (lane >> 4) << 2;
  const int colb = gq*128 + wv*16 + nq;
  const int brow = gb*16 + bb;
  const int bswz = (bb & 7) << 4;

  // staging role: row srow = tid&15, 8 packets p = j*512 + tid
  const int srow = tid & 15;
  const int scb = (tid >> 4) * 8;     // byte offset within row for j=0
  const int sswz = (srow & 7) << 4;

  // producer packet index
  const int pp = (gq*32 + wv*4 + (nq >> 2))*16 + bb;

  f32x4 xp = *(const f32x4*)(out + (size_t)brow*H_ + colb);

  for (int t = 0; t < T_; ++t) {
    unsigned char* hsb = lds + (size_t)(t & 1)*32768;
    unsigned char* sdst = hsb + srow*2048;
    if (t == 0) {
      u32x2 z = (u32x2){0u, 0u};
      #pragma unroll
      for (int j = 0; j < 8; ++j)
        *(u32x2*)(sdst + ((j*256 + scb) ^ sswz)) = z;
    } else {
      const unsigned want = (unsigned)t;
      const unsigned char* pb = hx + (size_t)(t & 1)*262144 + (size_t)gb*65536 + (size_t)tid*16;
      u32x4 v0,v1,v2,v3,v4,v5,v6,v7;
      __builtin_amdgcn_s_sleep(8);
      asm volatile(
        "global_load_dwordx4 %0, %8, off sc0 sc1\n\t"
        "global_load_dwordx4 %1, %9, off sc0 sc1\n\t"
        "global_load_dwordx4 %2, %10, off sc0 sc1\n\t"
        "global_load_dwordx4 %3, %11, off sc0 sc1\n\t"
        "global_load_dwordx4 %4, %12, off sc0 sc1\n\t"
        "global_load_dwordx4 %5, %13, off sc0 sc1\n\t"
        "global_load_dwordx4 %6, %14, off sc0 sc1\n\t"
        "global_load_dwordx4 %7, %15, off sc0 sc1"
        : "=&v"(v0),"=&v"(v1),"=&v"(v2),"=&v"(v3),"=&v"(v4),"=&v"(v5),"=&v"(v6),"=&v"(v7)
        : "v"(pb), "v"(pb+8192), "v"(pb+2*8192), "v"(pb+3*8192),
          "v"(pb+4*8192), "v"(pb+5*8192), "v"(pb+6*8192), "v"(pb+7*8192)
        : "memory");
      asm volatile("s_waitcnt vmcnt(0)"
        : "+v"(v0),"+v"(v1),"+v"(v2),"+v"(v3),"+v"(v4),"+v"(v5),"+v"(v6),"+v"(v7)
        :: "memory");
      unsigned m;
      #define MKMASK() { m = 0; \
        m |= (v0[2]==want) ? 1u<<0 : 0u;  m |= (v1[2]==want) ? 1u<<1 : 0u; \
        m |= (v2[2]==want) ? 1u<<2 : 0u;  m |= (v3[2]==want) ? 1u<<3 : 0u; \
        m |= (v4[2]==want) ? 1u<<4 : 0u;  m |= (v5[2]==want) ? 1u<<5 : 0u; \
        m |= (v6[2]==want) ? 1u<<6 : 0u;  m |= (v7[2]==want) ? 1u<<7 : 0u; }
      MKMASK()
      while (m != 0xffu) {
        __builtin_amdgcn_s_sleep(1);
        #define RLD(vv, jj) if (!((m >> (jj)) & 1u)) \
          asm volatile("global_load_dwordx4 %0, %1, off sc0 sc1" \
                       : "=&v"(vv) : "v"(pb + (jj)*8192) : "memory");
        RLD(v0,0) RLD(v1,1) RLD(v2,2) RLD(v3,3)
        RLD(v4,4) RLD(v5,5) RLD(v6,6) RLD(v7,7)
        #undef RLD
        asm volatile("s_waitcnt vmcnt(0)"
          : "+v"(v0),"+v"(v1),"+v"(v2),"+v"(v3),"+v"(v4),"+v"(v5),"+v"(v6),"+v"(v7)
          :: "memory");
        MKMASK()
      }
      #undef MKMASK
      #define STG(vv, jj) \
        *(u32x2*)(sdst + (((jj)*256 + scb) ^ sswz)) = (u32x2){vv[0], vv[1]};
      STG(v0,0) STG(v1,1) STG(v2,2) STG(v3,3)
      STG(v4,4) STG(v5,5) STG(v6,6) STG(v7,7)
      #undef STG
    }
    // single barrier per step: LDS-only drain (global stores/loads stay in flight)
    asm volatile("s_waitcnt lgkmcnt(0)\n\ts_barrier" ::: "memory");

    const unsigned char* hfrow = hsb + (size_t)bb*2048;
    f32x4 acc0 = (f32x4){0.f,0.f,0.f,0.f}, acc1 = acc0, acc2 = acc0, acc3 = acc0;
    #pragma unroll
    for (int kb = 0; kb < 32; kb += 4) {
      short8 b0 = *(const short8*)(hfrow + ((kb*64 + klane) ^ bswz));
      short8 b1 = *(const short8*)(hfrow + (((kb+1)*64 + klane) ^ bswz));
      short8 b2 = *(const short8*)(hfrow + (((kb+2)*64 + klane) ^ bswz));
      short8 b3 = *(const short8*)(hfrow + (((kb+3)*64 + klane) ^ bswz));
      acc0 = __builtin_amdgcn_mfma_f32_16x16x32_bf16(af[kb],   b0, acc0, 0, 0, 0);
      acc1 = __builtin_amdgcn_mfma_f32_16x16x32_bf16(af[kb+1], b1, acc1, 0, 0, 0);
      acc2 = __builtin_amdgcn_mfma_f32_16x16x32_bf16(af[kb+2], b2, acc2, 0, 0, 0);
      acc3 = __builtin_amdgcn_mfma_f32_16x16x32_bf16(af[kb+3], b3, acc3, 0, 0, 0);
    }
    f32x4 hval;
    #pragma unroll
    for (int q = 0; q < 4; ++q)
      hval[q] = tanhf((acc0[q] + acc1[q]) + (acc2[q] + acc3[q]) + xp[q]);

    // tagged packet, fire-and-forget system-scope store
    u32x4 pkt;
    pkt[0] = f2bf(hval[0]) | ((unsigned)f2bf(hval[1]) << 16);
    pkt[1] = f2bf(hval[2]) | ((unsigned)f2bf(hval[3]) << 16);
    pkt[2] = (unsigned)(t + 1);
    pkt[3] = 0u;
    const unsigned char* wp = hx + (size_t)((t+1) & 1)*262144 + (size_t)gb*65536
                              + (size_t)pp*16;
    asm volatile("global_store_dwordx4 %0, %1, off sc0 sc1" :: "v"(wp), "v"(pkt) : "memory");

    // f32 outputs (off the handshake path)
    *(f32x4*)(out + (size_t)t*BH + (size_t)brow*H_ + colb) = hval;
    if (t == T_-1)
      *(f32x4*)(out + (size_t)T_*BH + (size_t)brow*H_ + colb) = hval;

    int tn = (t < T_-1) ? t+1 : t;
    xp = *(const f32x4*)(out + (size_t)tn*BH + (size_t)brow*H_ + colb);
  }
}

extern "C" void kernel_launch(void* const* d_in, const int* in_sizes, int n_in,
                              void* d_out, int out_size, void* d_ws, size_t ws_size,
                              hipStream_t stream)
{
  const float* in  = (const float*)d_in[0];
  const float* wih = (const float*)d_in[1];
  const float* whh = (const float*)d_in[2];
  const float* bih = (const float*)d_in[3];
  const float* bhh = (const float*)d_in[4];
  float* out = (float*)d_out;
  unsigned char* ws = (unsigned char*)d_ws;

  unsigned char*  hx    = ws;                                        // 2 x 4 x 64KB tagged buffers
  unsigned short* wih_b = (unsigned short*)(ws + 524288);            // 2MB
  unsigned short* whh_b = (unsigned short*)(ws + 524288 + 2097152);  // 2MB
  unsigned short* inb   = (unsigned short*)(ws + 524288 + 4194304);  // 64MB bf16 input (R-major)

  hipMemsetAsync(hx, 0, 524288, stream);   // clear stale tags (graph-replay safe)
  convert_weights<<<1024, 256, 0, stream>>>((const f32x4*)wih, (const f32x4*)whh,
                                            (uint2*)wih_b, (uint2*)whh_b);
  convert_input<<<16384, 256, 0, stream>>>(in, inb);
  gemm_xproj<<<dim3(8, 256), 256, 0, stream>>>(inb, wih_b, bih, bhh, out);
  rnn_recur<<<32, 512, 131072, stream>>>(whh_b, out, hx);
}

// Round 16
// 1553.715 us; speedup vs baseline: 1.0864x; 1.0864x over previous
//
#include <hip/hip_runtime.h>
#include <hip/hip_bf16.h>
#include <stdint.h>

#define B_ 64
#define T_ 512
#define I_ 1024
#define H_ 1024
#define BH (B_*H_)

typedef __attribute__((ext_vector_type(8))) short short8;
typedef __attribute__((ext_vector_type(4))) float f32x4;
typedef __attribute__((ext_vector_type(4))) unsigned u32x4;
typedef __attribute__((ext_vector_type(2))) unsigned u32x2;

static __device__ __forceinline__ unsigned short f2bf(float f) {
  union { float f; unsigned u; } v; v.f = f;
  unsigned r = v.u + 0x7fffu + ((v.u >> 16) & 1u);
  return (unsigned short)(r >> 16);
}

static __device__ __forceinline__ void glds16(const void* g, void* l) {
  __builtin_amdgcn_global_load_lds(
      (const __attribute__((address_space(1))) unsigned int*)g,
      (__attribute__((address_space(3))) unsigned int*)l, 16, 0, 0);
}

// ---------------- fused conversion: blocks 0..1023 weights, 1024.. input ----------------
__global__ void convert_all(const f32x4* __restrict__ wih, const f32x4* __restrict__ whh,
                            uint2* __restrict__ wih_b, uint2* __restrict__ whh_b,
                            const float* __restrict__ in, unsigned short* __restrict__ inb)
{
  if (blockIdx.x < 1024) {
    int idx = blockIdx.x * 256 + threadIdx.x;
    f32x4 a = wih[idx];
    uint2 o;
    o.x = f2bf(a[0]) | ((unsigned)f2bf(a[1]) << 16);
    o.y = f2bf(a[2]) | ((unsigned)f2bf(a[3]) << 16);
    wih_b[idx] = o;
    f32x4 b = whh[idx];
    uint2 p;
    p.x = f2bf(b[0]) | ((unsigned)f2bf(b[1]) << 16);
    p.y = f2bf(b[2]) | ((unsigned)f2bf(b[3]) << 16);
    whh_b[idx] = p;
  } else {
    size_t idx = (size_t)(blockIdx.x - 1024) * 256 + threadIdx.x;
    size_t base = idx * 8;
    size_t R = base >> 10;
    int i = (int)(base & 1023);
    int b = (int)(R & 63), t = (int)(R >> 6);
    const float* src = in + ((size_t)b * T_ + (size_t)t) * I_ + i;
    f32x4 x0 = *(const f32x4*)src;
    f32x4 x1 = *(const f32x4*)(src + 4);
    uint4 o;
    o.x = f2bf(x0[0]) | ((unsigned)f2bf(x0[1]) << 16);
    o.y = f2bf(x0[2]) | ((unsigned)f2bf(x0[3]) << 16);
    o.z = f2bf(x1[0]) | ((unsigned)f2bf(x1[1]) << 16);
    o.w = f2bf(x1[2]) | ((unsigned)f2bf(x1[3]) << 16);
    *(uint4*)(inb + base) = o;
  }
}

// ---------------- x_proj GEMM: both operands via global_load_lds ----------------
__launch_bounds__(256)
__global__ void gemm_xproj(const unsigned short* __restrict__ inb,
                           const unsigned short* __restrict__ wb,
                           const float* __restrict__ bih,
                           const float* __restrict__ bhh,
                           float* __restrict__ out)
{
  __shared__ __align__(16) unsigned char As[16384];
  __shared__ __align__(16) unsigned char Bs[16384];
  const int tid = threadIdx.x;
  const int lane = tid & 63;
  const int w = tid >> 6;
  const int wm = w >> 1, wn = w & 1;
  const int bn = blockIdx.x, bm = blockIdx.y;

  f32x4 acc[4][4];
  #pragma unroll
  for (int i = 0; i < 4; ++i)
    #pragma unroll
    for (int j = 0; j < 4; ++j)
      acc[i][j] = (f32x4){0.f,0.f,0.f,0.f};

  for (int kt = 0; kt < 16; ++kt) {
    __syncthreads();
    #pragma unroll
    for (int q = 0; q < 4; ++q) {
      int inst = w*4 + q;
      int rr = inst*8 + (lane >> 3);
      int soA = ((bm*128 + rr) * I_ + kt*64) * 2 + (((lane & 7) * 16) ^ ((rr & 7) << 4));
      int soB = ((bn*128 + rr) * I_ + kt*64) * 2 + (((lane & 7) * 16) ^ ((rr & 7) << 4));
      glds16((const unsigned char*)inb + soA, As + inst*1024);
      glds16((const unsigned char*)wb  + soB, Bs + inst*1024);
    }
    __syncthreads();
    #pragma unroll
    for (int kb = 0; kb < 2; ++kb) {
      const int kby = kb*64 + ((lane >> 4) << 4);
      short8 af[4], bfr[4];
      #pragma unroll
      for (int i = 0; i < 4; ++i) {
        int ra = wm*64 + i*16 + (lane & 15);
        af[i] = *(const short8*)(As + ra*128 + (kby ^ ((ra & 7) << 4)));
      }
      #pragma unroll
      for (int j = 0; j < 4; ++j) {
        int rb2 = wn*64 + j*16 + (lane & 15);
        bfr[j] = *(const short8*)(Bs + rb2*128 + (kby ^ ((rb2 & 7) << 4)));
      }
      #pragma unroll
      for (int i = 0; i < 4; ++i)
        #pragma unroll
        for (int j = 0; j < 4; ++j)
          acc[i][j] = __builtin_amdgcn_mfma_f32_16x16x32_bf16(af[i], bfr[j], acc[i][j], 0, 0, 0);
    }
  }
  #pragma unroll
  for (int j = 0; j < 4; ++j) {
    int col = bn*128 + wn*64 + j*16 + (lane & 15);
    float bias = bih[col] + bhh[col];
    #pragma unroll
    for (int i = 0; i < 4; ++i) {
      int Rb = bm*128 + wm*64 + i*16 + ((lane >> 4) << 2);
      #pragma unroll
      for (int q = 0; q < 4; ++q) {
        int R = Rb + q;
        out[(size_t)(R >> 6) * BH + (size_t)(R & 63) * H_ + col] = acc[i][j][q] + bias;
      }
    }
  }
}

// ---------------- recurrence: R13 transport (best verified) ----------------
// 64 WGs: gb=g>>4 (16 batch rows), gn=g&15 (64 H cols). Packet P = gn*256 + tid
// holds 4 bf16 + tag t+1, system-scope. sleep(8) then one 16-load sweep; on miss,
// re-load ONLY the missing packets (batched conditional loads + one drain).
__launch_bounds__(256, 1)
__global__ void rnn_recur(const unsigned short* __restrict__ whh_b,
                          float* __restrict__ out,
                          unsigned char* __restrict__ hx)
{
  extern __shared__ __align__(16) unsigned char lds[];
  const int tid = threadIdx.x;
  const int lane = tid & 63;
  const int w = tid >> 6;
  const int g = blockIdx.x;
  const int gb = g >> 4;
  const int gn = g & 15;

  // ---- one-time W_hh slice: global -> LDS (swizzled) -> registers ----
  for (int q = 0; q < 32; ++q) {
    int inst = w*32 + q;
    int nl = inst >> 1;
    int koff = (inst & 1)*1024 + lane*16;
    size_t srcoff = (size_t)(gn*64 + nl)*2048 + (size_t)(koff ^ ((nl & 7) << 4));
    glds16((const unsigned char*)whh_b + srcoff, lds + inst*1024);
  }
  asm volatile("s_waitcnt vmcnt(0)" ::: "memory");
  __syncthreads();

  const int arow = w*16 + (lane & 15);
  const unsigned char* wsrow = lds + (size_t)arow*2048;
  const int aswz = (arow & 7) << 4;
  const int klane = (lane >> 4) << 4;
  short8 af[32];
  #pragma unroll
  for (int kb = 0; kb < 32; ++kb)
    af[kb] = *(const short8*)(wsrow + ((kb*64 + klane) ^ aswz));
  __syncthreads();   // W region reused as hs double-buffer below

  const int bb = lane & 15;
  const int nq = (lane >> 4) << 2;
  const int colb = gn*64 + w*16 + nq;
  const int brow = gb*16 + bb;
  const int bswz = (bb & 7) << 4;

  // staging role
  const int srow = tid & 15;
  const int scol = tid >> 4;
  const int sswz = (srow & 7) << 4;

  f32x4 xp = *(const f32x4*)(out + (size_t)brow*H_ + colb);

  for (int t = 0; t < T_; ++t) {
    unsigned char* hsb = lds + (size_t)(t & 1)*32768;
    unsigned char* sdst = hsb + srow*2048;
    if (t == 0) {
      u32x2 z = (u32x2){0u, 0u};
      #pragma unroll
      for (int j = 0; j < 16; ++j)
        *(u32x2*)(sdst + (((j*16 + scol)*8) ^ sswz)) = z;
    } else {
      const unsigned want = (unsigned)t;
      const unsigned char* pb = hx + (size_t)(t & 1)*262144 + (size_t)gb*65536 + (size_t)tid*16;
      u32x4 v0,v1,v2,v3,v4,v5,v6,v7,v8,v9,v10,v11,v12,v13,v14,v15;
      __builtin_amdgcn_s_sleep(8);   // let producer stores reach MALL before sweep #1
      // full batched sweep: 16 parallel loads, one drain
      asm volatile(
        "global_load_dwordx4 %0, %8, off sc0 sc1\n\t"
        "global_load_dwordx4 %1, %9, off sc0 sc1\n\t"
        "global_load_dwordx4 %2, %10, off sc0 sc1\n\t"
        "global_load_dwordx4 %3, %11, off sc0 sc1\n\t"
        "global_load_dwordx4 %4, %12, off sc0 sc1\n\t"
        "global_load_dwordx4 %5, %13, off sc0 sc1\n\t"
        "global_load_dwordx4 %6, %14, off sc0 sc1\n\t"
        "global_load_dwordx4 %7, %15, off sc0 sc1"
        : "=&v"(v0),"=&v"(v1),"=&v"(v2),"=&v"(v3),"=&v"(v4),"=&v"(v5),"=&v"(v6),"=&v"(v7)
        : "v"(pb), "v"(pb+4096), "v"(pb+2*4096), "v"(pb+3*4096),
          "v"(pb+4*4096), "v"(pb+5*4096), "v"(pb+6*4096), "v"(pb+7*4096)
        : "memory");
      asm volatile(
        "global_load_dwordx4 %0, %8, off sc0 sc1\n\t"
        "global_load_dwordx4 %1, %9, off sc0 sc1\n\t"
        "global_load_dwordx4 %2, %10, off sc0 sc1\n\t"
        "global_load_dwordx4 %3, %11, off sc0 sc1\n\t"
        "global_load_dwordx4 %4, %12, off sc0 sc1\n\t"
        "global_load_dwordx4 %5, %13, off sc0 sc1\n\t"
        "global_load_dwordx4 %6, %14, off sc0 sc1\n\t"
        "global_load_dwordx4 %7, %15, off sc0 sc1"
        : "=&v"(v8),"=&v"(v9),"=&v"(v10),"=&v"(v11),"=&v"(v12),"=&v"(v13),"=&v"(v14),"=&v"(v15)
        : "v"(pb+8*4096), "v"(pb+9*4096), "v"(pb+10*4096), "v"(pb+11*4096),
          "v"(pb+12*4096), "v"(pb+13*4096), "v"(pb+14*4096), "v"(pb+15*4096)
        : "memory");
      asm volatile("s_waitcnt vmcnt(0)"
        : "+v"(v0),"+v"(v1),"+v"(v2),"+v"(v3),"+v"(v4),"+v"(v5),"+v"(v6),"+v"(v7),
          "+v"(v8),"+v"(v9),"+v"(v10),"+v"(v11),"+v"(v12),"+v"(v13),"+v"(v14),"+v"(v15)
        :: "memory");
      unsigned m;
      #define MKMASK() { m = 0; \
        m |= (v0[2]==want)  ? 1u<<0  : 0u;  m |= (v1[2]==want)  ? 1u<<1  : 0u; \
        m |= (v2[2]==want)  ? 1u<<2  : 0u;  m |= (v3[2]==want)  ? 1u<<3  : 0u; \
        m |= (v4[2]==want)  ? 1u<<4  : 0u;  m |= (v5[2]==want)  ? 1u<<5  : 0u; \
        m |= (v6[2]==want)  ? 1u<<6  : 0u;  m |= (v7[2]==want)  ? 1u<<7  : 0u; \
        m |= (v8[2]==want)  ? 1u<<8  : 0u;  m |= (v9[2]==want)  ? 1u<<9  : 0u; \
        m |= (v10[2]==want) ? 1u<<10 : 0u;  m |= (v11[2]==want) ? 1u<<11 : 0u; \
        m |= (v12[2]==want) ? 1u<<12 : 0u;  m |= (v13[2]==want) ? 1u<<13 : 0u; \
        m |= (v14[2]==want) ? 1u<<14 : 0u;  m |= (v15[2]==want) ? 1u<<15 : 0u; }
      MKMASK()
      while (m != 0xffffu) {
        __builtin_amdgcn_s_sleep(1);
        // partial resweep: only missing packets (batched, one drain)
        #define RLD(vv, jj) if (!((m >> (jj)) & 1u)) \
          asm volatile("global_load_dwordx4 %0, %1, off sc0 sc1" \
                       : "=&v"(vv) : "v"(pb + (jj)*4096) : "memory");
        RLD(v0,0)  RLD(v1,1)  RLD(v2,2)  RLD(v3,3)
        RLD(v4,4)  RLD(v5,5)  RLD(v6,6)  RLD(v7,7)
        RLD(v8,8)  RLD(v9,9)  RLD(v10,10) RLD(v11,11)
        RLD(v12,12) RLD(v13,13) RLD(v14,14) RLD(v15,15)
        #undef RLD
        asm volatile("s_waitcnt vmcnt(0)"
          : "+v"(v0),"+v"(v1),"+v"(v2),"+v"(v3),"+v"(v4),"+v"(v5),"+v"(v6),"+v"(v7),
            "+v"(v8),"+v"(v9),"+v"(v10),"+v"(v11),"+v"(v12),"+v"(v13),"+v"(v14),"+v"(v15)
          :: "memory");
        MKMASK()
      }
      #undef MKMASK
      // stage all 16 payloads
      #define STG(vv, jj) \
        *(u32x2*)(sdst + ((((jj)*16 + scol)*8) ^ sswz)) = (u32x2){vv[0], vv[1]};
      STG(v0,0)  STG(v1,1)  STG(v2,2)  STG(v3,3)
      STG(v4,4)  STG(v5,5)  STG(v6,6)  STG(v7,7)
      STG(v8,8)  STG(v9,9)  STG(v10,10) STG(v11,11)
      STG(v12,12) STG(v13,13) STG(v14,14) STG(v15,15)
      #undef STG
    }
    // single barrier per step: LDS-only drain (global stores/loads stay in flight)
    asm volatile("s_waitcnt lgkmcnt(0)\n\ts_barrier" ::: "memory");

    const unsigned char* hfrow = hsb + (size_t)bb*2048;
    f32x4 acc0 = (f32x4){0.f,0.f,0.f,0.f}, acc1 = acc0, acc2 = acc0, acc3 = acc0;
    #pragma unroll
    for (int kb = 0; kb < 32; kb += 4) {
      short8 b0 = *(const short8*)(hfrow + ((kb*64 + klane) ^ bswz));
      short8 b1 = *(const short8*)(hfrow + (((kb+1)*64 + klane) ^ bswz));
      short8 b2 = *(const short8*)(hfrow + (((kb+2)*64 + klane) ^ bswz));
      short8 b3 = *(const short8*)(hfrow + (((kb+3)*64 + klane) ^ bswz));
      acc0 = __builtin_amdgcn_mfma_f32_16x16x32_bf16(af[kb],   b0, acc0, 0, 0, 0);
      acc1 = __builtin_amdgcn_mfma_f32_16x16x32_bf16(af[kb+1], b1, acc1, 0, 0, 0);
      acc2 = __builtin_amdgcn_mfma_f32_16x16x32_bf16(af[kb+2], b2, acc2, 0, 0, 0);
      acc3 = __builtin_amdgcn_mfma_f32_16x16x32_bf16(af[kb+3], b3, acc3, 0, 0, 0);
    }
    f32x4 hval;
    #pragma unroll
    for (int q = 0; q < 4; ++q)
      hval[q] = tanhf((acc0[q] + acc1[q]) + (acc2[q] + acc3[q]) + xp[q]);

    // tagged packet, fire-and-forget system-scope store
    u32x4 pkt;
    pkt[0] = f2bf(hval[0]) | ((unsigned)f2bf(hval[1]) << 16);
    pkt[1] = f2bf(hval[2]) | ((unsigned)f2bf(hval[3]) << 16);
    pkt[2] = (unsigned)(t + 1);
    pkt[3] = 0u;
    const unsigned char* wp = hx + (size_t)((t+1) & 1)*262144 + (size_t)gb*65536
                              + (size_t)(gn*256 + tid)*16;
    asm volatile("global_store_dwordx4 %0, %1, off sc0 sc1" :: "v"(wp), "v"(pkt) : "memory");

    // f32 outputs (off the handshake path)
    *(f32x4*)(out + (size_t)t*BH + (size_t)brow*H_ + colb) = hval;
    if (t == T_-1)
      *(f32x4*)(out + (size_t)T_*BH + (size_t)brow*H_ + colb) = hval;

    int tn = (t < T_-1) ? t+1 : t;
    xp = *(const f32x4*)(out + (size_t)tn*BH + (size_t)brow*H_ + colb);
  }
}

extern "C" void kernel_launch(void* const* d_in, const int* in_sizes, int n_in,
                              void* d_out, int out_size, void* d_ws, size_t ws_size,
                              hipStream_t stream)
{
  const float* in  = (const float*)d_in[0];
  const float* wih = (const float*)d_in[1];
  const float* whh = (const float*)d_in[2];
  const float* bih = (const float*)d_in[3];
  const float* bhh = (const float*)d_in[4];
  float* out = (float*)d_out;
  unsigned char* ws = (unsigned char*)d_ws;

  unsigned char*  hx    = ws;                                        // 2 x 4 x 64KB tagged buffers
  unsigned short* wih_b = (unsigned short*)(ws + 524288);            // 2MB
  unsigned short* whh_b = (unsigned short*)(ws + 524288 + 2097152);  // 2MB
  unsigned short* inb   = (unsigned short*)(ws + 524288 + 4194304);  // 64MB bf16 input (R-major)

  hipMemsetAsync(hx, 0, 524288, stream);   // clear stale tags (graph-replay safe)
  convert_all<<<17408, 256, 0, stream>>>((const f32x4*)wih, (const f32x4*)whh,
                                         (uint2*)wih_b, (uint2*)whh_b, in, inb);
  gemm_xproj<<<dim3(8, 256), 256, 0, stream>>>(inb, wih_b, bih, bhh, out);
  rnn_recur<<<64, 256, 131072, stream>>>(whh_b, out, hx);
}